// Round 2
// baseline (265.480 us; speedup 1.0000x reference)
//
#include <hip/hip_runtime.h>

// Patch-embedding rearrange: (B=256, C=3, H=224, W=224) fp32 -> (B, 196, 768)
// out[b][ph*14+pw][c*256+i*16+j] = in[b][c][ph*16+i][pw*16+j]
//
// Strategy: one block per (b, ph) slab, staged through LDS.
//  - Read side:  per (b,c,ph) the 16 image rows are CONTIGUOUS (16*224 floats),
//    so the block reads 3 contiguous 14336 B chunks, fully coalesced float4.
//  - Write side: the 14 output rows p=ph*14..ph*14+13 are CONTIGUOUS
//    (14*768 floats = 43008 B), fully coalesced float4.
//  - LDS rows padded 224 -> 228 floats (keeps 16B align; stride%32banks = 4
//    balances the permuted b128 reads across bank groups).

constexpr int B   = 256;
constexpr int C   = 3;
constexpr int H   = 224;
constexpr int W   = 224;
constexpr int P   = 16;
constexpr int PHN = H / P;              // 14
constexpr int PWN = W / P;              // 14
constexpr int W4  = W / 4;              // 56 float4 per image row
constexpr int LDS_STRIDE4 = 57;         // 228 floats / 4 (pad +1 float4)
constexpr int CHUNK4 = P * W4;          // 896 float4 per (c) chunk
constexpr int SLAB4  = C * CHUNK4;      // 2688 float4 per slab (in == out size)
constexpr int E4     = C * P * P / 4;   // 192 float4 per output row

__global__ __launch_bounds__(256)
void patch_slab_kernel(const float4* __restrict__ in, float4* __restrict__ out) {
    __shared__ float4 lds4[C * P * LDS_STRIDE4];   // 3*16*57*16B = 43776 B

    const int tid  = threadIdx.x;
    const int slab = blockIdx.x;        // 0 .. B*PHN-1
    const int ph   = slab % PHN;
    const int b    = slab / PHN;

    // ---- load: 3 contiguous chunks -> LDS (row stride padded) ----
    // chunk c base (in float4s): ((b*C + c)*H + ph*P) * W4
    #pragma unroll
    for (int v = tid; v < SLAB4; v += 256) {
        int c    = v / CHUNK4;           // 0..2
        int f4   = v - c * CHUNK4;       // 0..895
        int i    = f4 / W4;              // 0..15 row inside patch band
        int col4 = f4 - i * W4;          // 0..55
        size_t gidx = ((size_t)(b * C + c) * H + (size_t)ph * P + i) * W4 + col4;
        lds4[(c * P + i) * LDS_STRIDE4 + col4] = in[gidx];
    }

    __syncthreads();

    // ---- store: permuted LDS read -> one contiguous 43008 B output region ----
    // out float4 index within slab: v = ((pw*C + c)*P + i)*4 + j4
    float4* dst = out + (size_t)(b * PHN + ph) * PWN * E4;
    #pragma unroll
    for (int v = tid; v < SLAB4; v += 256) {
        int j4 = v & 3;                  // float4 col inside patch row
        int i  = (v >> 2) & (P - 1);     // row inside patch
        int c  = (v >> 6) % C;           // channel
        int pw = v / (C * P * 4);        // patch column, 0..13
        dst[v] = lds4[(c * P + i) * LDS_STRIDE4 + pw * 4 + j4];
    }
}

extern "C" void kernel_launch(void* const* d_in, const int* in_sizes, int n_in,
                              void* d_out, int out_size, void* d_ws, size_t ws_size,
                              hipStream_t stream) {
    const float4* in  = (const float4*)d_in[0];
    float4*       out = (float4*)d_out;
    patch_slab_kernel<<<B * PHN, 256, 0, stream>>>(in, out);
}

// Round 3
// 261.906 us; speedup vs baseline: 1.0136x; 1.0136x over previous
//
#include <hip/hip_runtime.h>

// Patch-embedding rearrange: (B=256, C=3, H=224, W=224) fp32 -> (B, 196, 768)
// out[b][ph*14+pw][c*256+i*16+j] = in[b][c][ph*16+i][pw*16+j]
//
// R3: half-slab blocks. One block per (b, ph, h) where h picks rows i in
// [8h, 8h+8). Why:
//  - LDS = 24 rows x 57 float4 = 21.9 KB -> 4 blocks/CU (28/32 waves) vs 3.
//  - TPB=448 gives EXACTLY 3 float4 per thread -> compile-time unrolled,
//    BATCHED loads (Q=3 in flight) instead of load->vmcnt(0)->ds_write serial.
//  - Reads: 3 contiguous 7168 B chunks per block (coalesced float4).
//  - Writes: per (pw,c) a 32-float4 (512 B, 512 B-aligned) contiguous run;
//    each wave writes two full runs -> fully coalesced.
//  - LDS stride 57 (odd): bank-group residue (c*8+il + 4pw + j4) mod 8 is
//    uniform (8 lanes/group) in both phases -> conflict-free b128.

constexpr int B    = 256;
constexpr int C    = 3;
constexpr int H    = 224;
constexpr int P    = 16;
constexpr int PHN  = 14;
constexpr int PWN  = 14;
constexpr int W4   = 56;                 // float4 per image row
constexpr int HALF = 8;                  // rows per half-slab
constexpr int LDSS = 57;                 // padded LDS row stride (float4)
constexpr int NV   = C * HALF * W4;      // 1344 float4 per half-slab
constexpr int TPB  = 448;                // 7 waves
constexpr int ITERS = NV / TPB;          // 3, exact

__global__ __launch_bounds__(TPB)
void patch_half_kernel(const float4* __restrict__ in, float4* __restrict__ out) {
    __shared__ float4 lds4[C * HALF * LDSS];   // 24*57*16 B = 21888 B

    const int tid = threadIdx.x;
    int blk = blockIdx.x;                // 0 .. B*PHN*2-1
    const int h  = blk & 1;
    blk >>= 1;
    const int ph = blk % PHN;
    const int b  = blk / PHN;

    // ---- phase 1: batched global loads -> regs -> LDS ----
    float4 r[ITERS];
    #pragma unroll
    for (int k = 0; k < ITERS; ++k) {
        int v   = tid + k * TPB;         // 0..1343
        int c   = v / (HALF * W4);       // 0..2
        int rem = v - c * (HALF * W4);
        int il  = rem / W4;              // 0..7
        int col = rem - il * W4;         // 0..55
        int gidx = ((b * C + c) * H + ph * P + h * HALF + il) * W4 + col;
        r[k] = in[gidx];
    }
    #pragma unroll
    for (int k = 0; k < ITERS; ++k) {
        int v   = tid + k * TPB;
        int c   = v / (HALF * W4);
        int rem = v - c * (HALF * W4);
        int il  = rem / W4;
        int col = rem - il * W4;
        lds4[(c * HALF + il) * LDSS + col] = r[k];
    }
    __syncthreads();

    // ---- phase 2: batched LDS reads -> regs -> global stores ----
    // v enumerates output order: v = ((pw*C + c)*HALF + il)*4 + j4
    float4 s[ITERS];
    #pragma unroll
    for (int k = 0; k < ITERS; ++k) {
        int v  = tid + k * TPB;
        int j4 = v & 3;
        int il = (v >> 2) & (HALF - 1);
        int g  = v >> 5;                 // pw*C + c
        int c  = g % C;
        int pw = g / C;
        s[k] = lds4[(c * HALF + il) * LDSS + pw * 4 + j4];
    }
    const int obase = (b * (PHN * PWN) + ph * PWN) * 192 + h * (HALF * 4);
    #pragma unroll
    for (int k = 0; k < ITERS; ++k) {
        int v  = tid + k * TPB;
        int j4 = v & 3;
        int il = (v >> 2) & (HALF - 1);
        int g  = v >> 5;
        int c  = g % C;
        int pw = g / C;
        out[obase + pw * 192 + c * 64 + il * 4 + j4] = s[k];
    }
}

extern "C" void kernel_launch(void* const* d_in, const int* in_sizes, int n_in,
                              void* d_out, int out_size, void* d_ws, size_t ws_size,
                              hipStream_t stream) {
    const float4* in  = (const float4*)d_in[0];
    float4*       out = (float4*)d_out;
    patch_half_kernel<<<B * PHN * 2, TPB, 0, stream>>>(in, out);
}